// Round 2
// baseline (367.757 us; speedup 1.0000x reference)
//
#include <hip/hip_runtime.h>
#include <hip/hip_bf16.h>

#define D_MODEL 1024
#define BB 4
#define TT 2048
#define ROWS (BB*TT)     /* 8192 */
#define NCHUNK 16
#define CHLEN 128        /* NCHUNK*CHLEN == TT */

typedef __attribute__((ext_vector_type(8))) short short8;
typedef __attribute__((ext_vector_type(4))) float floatx4;

static __device__ __forceinline__ ushort f2bf(float f) {
    union { float f; unsigned u; } v; v.f = f;
    unsigned r = v.u + 0x7FFF + ((v.u >> 16) & 1);   // RNE
    return (ushort)(r >> 16);
}
static __device__ __forceinline__ float bf2f(ushort b) {
    union { unsigned u; float f; } v; v.u = ((unsigned)b) << 16;
    return v.f;
}

// ---------------- prep kernels ----------------

__global__ __launch_bounds__(256) void cvt_x(const float* __restrict__ x,
                                             ushort* __restrict__ xb) {
    int i = blockIdx.x * 256 + threadIdx.x;      // 2097152 threads, 1 float4 each
    float4 v = ((const float4*)x)[i];
    ushort4 o;
    o.x = f2bf(v.x); o.y = f2bf(v.y); o.z = f2bf(v.z); o.w = f2bf(v.w);
    ((ushort4*)xb)[i] = o;
}

// W: K x N (row-major) fp32  ->  WT: N x K (row-major) bf16
__global__ __launch_bounds__(256) void transp_cvt(const float* __restrict__ W,
                                                  ushort* __restrict__ WT,
                                                  int K, int N) {
    __shared__ float tile[32][33];
    int n0 = blockIdx.x * 32, k0 = blockIdx.y * 32;
    int tx = threadIdx.x & 31, ty = threadIdx.x >> 5;   // ty 0..7
#pragma unroll
    for (int j = 0; j < 4; ++j)
        tile[ty + j*8][tx] = W[(size_t)(k0 + ty + j*8) * N + n0 + tx];
    __syncthreads();
#pragma unroll
    for (int j = 0; j < 4; ++j)
        WT[(size_t)(n0 + ty + j*8) * K + k0 + tx] = f2bf(tile[tx][ty + j*8]);
}

__global__ void consts_k(const float* __restrict__ nu_log,
                         const float* __restrict__ theta_log,
                         const float* __restrict__ gamma_log,
                         float* __restrict__ fr, float* __restrict__ fi,
                         float* __restrict__ gm) {
    int c = blockIdx.x * 256 + threadIdx.x;
    if (c < D_MODEL) {
        float nu = expf(-expf(nu_log[c]));
        float th = expf(theta_log[c]);
        fr[c] = nu * cosf(th);
        fi[c] = nu * sinf(th);
        gm[c] = expf(gamma_log[c]);
    }
}

// ---------------- bf16 MFMA GEMM (128x128 tile, BK=32) ----------------
// A: M x K bf16 row-major; B: N x K bf16 row-major (i.e. B-transposed input)
// mode 0: outC[row*N+col] = acc + bias[col]
// mode 1: split epilogue for GEMM1 (N=4096): cols [0,1024) -> gamma*val into
//         out_r; [1024,2048) -> gamma*val into out_i; [2048,4096) -> bf16 o.
__global__ __launch_bounds__(256) void gemm_bf16(
    const ushort* __restrict__ A, const ushort* __restrict__ B,
    int K, int N, const float* __restrict__ bias, int mode,
    const float* __restrict__ gamma,
    float* __restrict__ out_r, float* __restrict__ out_i,
    ushort* __restrict__ out_o, float* __restrict__ outC) {
    __shared__ ushort As[128 * 32];
    __shared__ ushort Bs[128 * 32];
    int tid = threadIdx.x;
    int lane = tid & 63, wave = tid >> 6;
    int wm = (wave & 1) * 64, wn = (wave >> 1) * 64;
    int lr = lane & 15, q = lane >> 4;
    long m0 = (long)blockIdx.y * 128;
    long n0 = (long)blockIdx.x * 128;
    floatx4 acc[4][4] = {};

    int r0 = tid >> 2, c0 = (tid & 3) * 8;   // staging: thread -> (row, k-col)
    const ushort* Ap = A + (m0 + r0) * (long)K + c0;
    const ushort* Bp = B + (n0 + r0) * (long)K + c0;

    for (int kt = 0; kt < K; kt += 32) {
        __syncthreads();
        *(uint4*)&As[r0 * 32 + c0]        = *(const uint4*)(Ap + kt);
        *(uint4*)&As[(r0 + 64) * 32 + c0] = *(const uint4*)(Ap + (long)64 * K + kt);
        *(uint4*)&Bs[r0 * 32 + c0]        = *(const uint4*)(Bp + kt);
        *(uint4*)&Bs[(r0 + 64) * 32 + c0] = *(const uint4*)(Bp + (long)64 * K + kt);
        __syncthreads();
        short8 af[4], bfv[4];
#pragma unroll
        for (int r = 0; r < 4; ++r)
            af[r] = *(const short8*)&As[(wm + r * 16 + lr) * 32 + q * 8];
#pragma unroll
        for (int c = 0; c < 4; ++c)
            bfv[c] = *(const short8*)&Bs[(wn + c * 16 + lr) * 32 + q * 8];
#pragma unroll
        for (int r = 0; r < 4; ++r)
#pragma unroll
            for (int c = 0; c < 4; ++c)
                acc[r][c] = __builtin_amdgcn_mfma_f32_16x16x32_bf16(
                    af[r], bfv[c], acc[r][c], 0, 0, 0);
    }

#pragma unroll
    for (int r = 0; r < 4; ++r) {
#pragma unroll
        for (int c = 0; c < 4; ++c) {
            long col = n0 + wn + c * 16 + lr;
            float bv = bias[col];
#pragma unroll
            for (int g = 0; g < 4; ++g) {
                long row = m0 + wm + r * 16 + q * 4 + g;
                float val = acc[r][c][g] + bv;
                if (mode == 0) {
                    outC[row * (long)N + col] = val;
                } else {
                    if (col < 1024)
                        out_r[row * 1024 + col] = gamma[col] * val;
                    else if (col < 2048)
                        out_i[row * 1024 + (col - 1024)] = gamma[col - 1024] * val;
                    else
                        out_o[row * 2048 + (col - 2048)] = f2bf(val);
                }
            }
        }
    }
}

// ---------------- chunked complex scan ----------------
// h_t = f*h_{t-1} + in_t per (b, channel). 16 chunks of 128 steps.
// phase1: local scan in-place, record per-chunk final h.
__global__ __launch_bounds__(256) void scan_phase1(
    float* __restrict__ in_r, float* __restrict__ in_i,
    float* __restrict__ carry,
    const float* __restrict__ fr_, const float* __restrict__ fi_) {
    int t = blockIdx.x * 256 + threadIdx.x;  // 65536
    int c = t & 1023;
    int ck = (t >> 10) & (NCHUNK - 1);
    int b = t >> 14;
    float fr = fr_[c], fi = fi_[c];
    size_t base = ((size_t)(b * TT + ck * CHLEN)) * 1024 + c;
    float hr = 0.f, hi = 0.f;
#pragma unroll 4
    for (int j = 0; j < CHLEN; ++j) {
        size_t idx = base + (size_t)j * 1024;
        float r = in_r[idx], im = in_i[idx];
        float nhr = fr * hr - fi * hi + r;
        float nhi = fr * hi + fi * hr + im;
        hr = nhr; hi = nhi;
        in_r[idx] = hr; in_i[idx] = hi;
    }
    size_t ci = (((size_t)b * 1024 + c) * NCHUNK + ck) * 2;
    carry[ci] = hr; carry[ci + 1] = hi;
}

// phase3: recompute carry-in from chunk summaries, apply h_t += f^(j+1) * H.
__global__ __launch_bounds__(256) void scan_phase3(
    float* __restrict__ h_r, float* __restrict__ h_i,
    const float* __restrict__ carry,
    const float* __restrict__ fr_, const float* __restrict__ fi_) {
    int t = blockIdx.x * 256 + threadIdx.x;
    int c = t & 1023;
    int ck = (t >> 10) & (NCHUNK - 1);
    int b = t >> 14;
    if (ck == 0) return;                      // uniform per block
    float fr = fr_[c], fi = fi_[c];
    // A = f^CHLEN by repeated squaring (CHLEN = 128 = 2^7)
    float ar = fr, ai = fi;
#pragma unroll
    for (int s = 0; s < 7; ++s) {
        float nr = ar * ar - ai * ai, ni = 2.f * ar * ai;
        ar = nr; ai = ni;
    }
    float Hr = 0.f, Hi = 0.f;
    size_t cb = ((size_t)b * 1024 + c) * NCHUNK * 2;
    for (int k = 0; k < ck; ++k) {
        float cr = carry[cb + k * 2], cim = carry[cb + k * 2 + 1];
        float nHr = ar * Hr - ai * Hi + cr;
        float nHi = ar * Hi + ai * Hr + cim;
        Hr = nHr; Hi = nHi;
    }
    float pr = fr, pi = fi;
    size_t base = ((size_t)(b * TT + ck * CHLEN)) * 1024 + c;
#pragma unroll 4
    for (int j = 0; j < CHLEN; ++j) {
        size_t idx = base + (size_t)j * 1024;
        float r = h_r[idx], im = h_i[idx];
        h_r[idx] = r + (pr * Hr - pi * Hi);
        h_i[idx] = im + (pr * Hi + pi * Hr);
        float npr = pr * fr - pi * fi, npi = pr * fi + pi * fr;
        pr = npr; pi = npi;
    }
}

// ---------------- silu-gate + LayerNorm -> bf16 y ----------------
__global__ __launch_bounds__(256) void ln_fuse(
    const float* __restrict__ hr, const float* __restrict__ hi,
    const ushort* __restrict__ o, const float* __restrict__ lnw,
    const float* __restrict__ lnb, ushort* __restrict__ yb) {
    long row = blockIdx.x;
    int tid = threadIdx.x;
    float y[8];
    float s = 0.f, s2 = 0.f;
#pragma unroll
    for (int j = 0; j < 8; ++j) {
        int c = tid + j * 256;                  // 0..2047
        float ov = bf2f(o[row * 2048 + c]);
        float sg = 1.f / (1.f + __expf(-ov));
        float h = (j < 4) ? hr[row * 1024 + c] : hi[row * 1024 + c - 1024];
        float v = h * ov * sg;
        y[j] = v; s += v; s2 += v * v;
    }
#pragma unroll
    for (int off = 32; off > 0; off >>= 1) {
        s += __shfl_down(s, off, 64);
        s2 += __shfl_down(s2, off, 64);
    }
    __shared__ float red[8];
    int wv = tid >> 6;
    if ((tid & 63) == 0) { red[wv] = s; red[4 + wv] = s2; }
    __syncthreads();
    if (tid == 0) {
        red[0] = red[0] + red[1] + red[2] + red[3];
        red[4] = red[4] + red[5] + red[6] + red[7];
    }
    __syncthreads();
    s = red[0]; s2 = red[4];
    float mu = s * (1.f / 2048.f);
    float var = s2 * (1.f / 2048.f) - mu * mu;
    float rs = rsqrtf(var + 1e-5f);
#pragma unroll
    for (int j = 0; j < 8; ++j) {
        int c = tid + j * 256;
        float v = (y[j] - mu) * rs * lnw[c] + lnb[c];
        yb[row * 2048 + c] = f2bf(v);
    }
}

// ---------------- launch ----------------

extern "C" void kernel_launch(void* const* d_in, const int* in_sizes, int n_in,
                              void* d_out, int out_size, void* d_ws, size_t ws_size,
                              hipStream_t stream) {
    const float* x         = (const float*)d_in[0];
    const float* W_in      = (const float*)d_in[1];
    const float* b_in      = (const float*)d_in[2];
    const float* nu_log    = (const float*)d_in[3];
    const float* theta_log = (const float*)d_in[4];
    const float* gamma_log = (const float*)d_in[5];
    const float* ln_w      = (const float*)d_in[6];
    const float* ln_b      = (const float*)d_in[7];
    const float* W_out     = (const float*)d_in[8];
    const float* b_out     = (const float*)d_in[9];
    float* out = (float*)d_out;

    char* ws = (char*)d_ws;
    size_t off = 0;
    auto alloc = [&](size_t bytes) {
        char* p = ws + off;
        off += (bytes + 255) & ~(size_t)255;
        return p;
    };
    ushort* xb    = (ushort*)alloc((size_t)ROWS * 1024 * 2);   // 16.8 MB
    ushort* WinT  = (ushort*)alloc((size_t)4096 * 1024 * 2);   // 8.4 MB
    ushort* WoutT = (ushort*)alloc((size_t)1024 * 2048 * 2);   // 4.2 MB
    float*  fr    = (float*)alloc(1024 * 4);
    float*  fi    = (float*)alloc(1024 * 4);
    float*  gm    = (float*)alloc(1024 * 4);
    float*  in_r  = (float*)alloc((size_t)ROWS * 1024 * 4);    // 33.5 MB (h_r after scan)
    float*  in_i  = (float*)alloc((size_t)ROWS * 1024 * 4);    // 33.5 MB
    ushort* obuf  = (ushort*)alloc((size_t)ROWS * 2048 * 2);   // 33.5 MB
    float*  carry = (float*)alloc((size_t)BB * 1024 * NCHUNK * 2 * 4);
    ushort* yb    = (ushort*)alloc((size_t)ROWS * 2048 * 2);   // 33.5 MB

    cvt_x<<<ROWS * 1024 / 4 / 256, 256, 0, stream>>>(x, xb);
    transp_cvt<<<dim3(4096 / 32, 1024 / 32), 256, 0, stream>>>(W_in, WinT, 1024, 4096);
    transp_cvt<<<dim3(1024 / 32, 2048 / 32), 256, 0, stream>>>(W_out, WoutT, 2048, 1024);
    consts_k<<<4, 256, 0, stream>>>(nu_log, theta_log, gamma_log, fr, fi, gm);

    gemm_bf16<<<dim3(4096 / 128, ROWS / 128), 256, 0, stream>>>(
        xb, WinT, 1024, 4096, b_in, 1, gm, in_r, in_i, obuf, nullptr);

    scan_phase1<<<BB * 1024 * NCHUNK / 256, 256, 0, stream>>>(in_r, in_i, carry, fr, fi);
    scan_phase3<<<BB * 1024 * NCHUNK / 256, 256, 0, stream>>>(in_r, in_i, carry, fr, fi);

    ln_fuse<<<ROWS, 256, 0, stream>>>(in_r, in_i, obuf, ln_w, ln_b, yb);

    gemm_bf16<<<dim3(1024 / 128, ROWS / 128), 256, 0, stream>>>(
        yb, WoutT, 2048, 1024, b_out, 0, nullptr, nullptr, nullptr, nullptr, out);
}

// Round 3
// 357.558 us; speedup vs baseline: 1.0285x; 1.0285x over previous
//
#include <hip/hip_runtime.h>
#include <hip/hip_bf16.h>

#define D_MODEL 1024
#define BB 4
#define TT 2048
#define ROWS (BB*TT)     /* 8192 */
#define NCHUNK 32
#define CHLEN 64         /* NCHUNK*CHLEN == TT */

typedef __attribute__((ext_vector_type(8))) short short8;
typedef __attribute__((ext_vector_type(4))) float floatx4;

static __device__ __forceinline__ ushort f2bf(float f) {
    union { float f; unsigned u; } v; v.f = f;
    unsigned r = v.u + 0x7FFF + ((v.u >> 16) & 1);   // RNE
    return (ushort)(r >> 16);
}
static __device__ __forceinline__ float bf2f(ushort b) {
    union { unsigned u; float f; } v; v.u = ((unsigned)b) << 16;
    return v.f;
}

// async global->LDS, 16B per lane; LDS dest must be wave-uniform base + lane*16
#define GLOAD_LDS16(gp, lp)                                                 \
    __builtin_amdgcn_global_load_lds(                                       \
        (const __attribute__((address_space(1))) void*)(gp),                \
        (__attribute__((address_space(3))) void*)(lp), 16, 0, 0)

// ---------------- prep kernels ----------------

__global__ __launch_bounds__(256) void cvt_x(const float* __restrict__ x,
                                             ushort* __restrict__ xb) {
    int i = blockIdx.x * 256 + threadIdx.x;      // 1 float4 each
    float4 v = ((const float4*)x)[i];
    ushort4 o;
    o.x = f2bf(v.x); o.y = f2bf(v.y); o.z = f2bf(v.z); o.w = f2bf(v.w);
    ((ushort4*)xb)[i] = o;
}

// W: K x N (row-major) fp32  ->  WT: N x K (row-major) bf16
__global__ __launch_bounds__(256) void transp_cvt(const float* __restrict__ W,
                                                  ushort* __restrict__ WT,
                                                  int K, int N) {
    __shared__ float tile[32][33];
    int n0 = blockIdx.x * 32, k0 = blockIdx.y * 32;
    int tx = threadIdx.x & 31, ty = threadIdx.x >> 5;   // ty 0..7
#pragma unroll
    for (int j = 0; j < 4; ++j)
        tile[ty + j*8][tx] = W[(size_t)(k0 + ty + j*8) * N + n0 + tx];
    __syncthreads();
#pragma unroll
    for (int j = 0; j < 4; ++j)
        WT[(size_t)(n0 + ty + j*8) * K + k0 + tx] = f2bf(tile[tx][ty + j*8]);
}

__global__ void consts_k(const float* __restrict__ nu_log,
                         const float* __restrict__ theta_log,
                         const float* __restrict__ gamma_log,
                         float* __restrict__ fr, float* __restrict__ fi,
                         float* __restrict__ gm) {
    int c = blockIdx.x * 256 + threadIdx.x;
    if (c < D_MODEL) {
        float nu = expf(-expf(nu_log[c]));
        float th = expf(theta_log[c]);
        fr[c] = nu * cosf(th);
        fi[c] = nu * sinf(th);
        gm[c] = expf(gamma_log[c]);
    }
}

// ---------------- bf16 MFMA GEMM (128x128 tile, BK=32, async staging) -------
// A: M x K bf16 row-major; B: N x K bf16 row-major (B-transposed input)
// mode 0: outC[row*N+col] = acc + bias[col]
// mode 1: GEMM1 split epilogue (N=4096): cols [0,1024)->gamma*val->out_r;
//         [1024,2048)->gamma*val->out_i; [2048,4096)->bf16 out_o.
__global__ __launch_bounds__(256) void gemm_bf16(
    const ushort* __restrict__ A, const ushort* __restrict__ B,
    int K, int N, const float* __restrict__ bias, int mode,
    const float* __restrict__ gamma,
    float* __restrict__ out_r, float* __restrict__ out_i,
    ushort* __restrict__ out_o, float* __restrict__ outC) {
    __shared__ ushort As[128 * 32];
    __shared__ ushort Bs[128 * 32];
    int tid = threadIdx.x;
    int lane = tid & 63, wave = tid >> 6;
    int wm = (wave & 1) * 64, wn = (wave >> 1) * 64;
    int lr = lane & 15, q = lane >> 4;
    long m0 = (long)blockIdx.y * 128;
    long n0 = (long)blockIdx.x * 128;
    floatx4 acc[4][4] = {};

    int r0 = tid >> 2, c0 = (tid & 3) * 8;   // staging: LDS byte off == tid*16
    const ushort* Ap = A + (m0 + r0) * (long)K + c0;
    const ushort* Bp = B + (n0 + r0) * (long)K + c0;

    for (int kt = 0; kt < K; kt += 32) {
        __syncthreads();
        GLOAD_LDS16(Ap + kt,                 &As[tid * 8]);
        GLOAD_LDS16(Ap + (long)64 * K + kt,  &As[tid * 8 + 2048]);
        GLOAD_LDS16(Bp + kt,                 &Bs[tid * 8]);
        GLOAD_LDS16(Bp + (long)64 * K + kt,  &Bs[tid * 8 + 2048]);
        __syncthreads();   // compiler drains vmcnt before s_barrier
        short8 af[4], bfv[4];
#pragma unroll
        for (int r = 0; r < 4; ++r)
            af[r] = *(const short8*)&As[(wm + r * 16 + lr) * 32 + q * 8];
#pragma unroll
        for (int c = 0; c < 4; ++c)
            bfv[c] = *(const short8*)&Bs[(wn + c * 16 + lr) * 32 + q * 8];
#pragma unroll
        for (int r = 0; r < 4; ++r)
#pragma unroll
            for (int c = 0; c < 4; ++c)
                acc[r][c] = __builtin_amdgcn_mfma_f32_16x16x32_bf16(
                    af[r], bfv[c], acc[r][c], 0, 0, 0);
    }

#pragma unroll
    for (int r = 0; r < 4; ++r) {
#pragma unroll
        for (int c = 0; c < 4; ++c) {
            long col = n0 + wn + c * 16 + lr;
            float bv = bias[col];
#pragma unroll
            for (int g = 0; g < 4; ++g) {
                long row = m0 + wm + r * 16 + q * 4 + g;
                float val = acc[r][c][g] + bv;
                if (mode == 0) {
                    outC[row * (long)N + col] = val;
                } else {
                    if (col < 1024)
                        out_r[row * 1024 + col] = gamma[col] * val;
                    else if (col < 2048)
                        out_i[row * 1024 + (col - 1024)] = gamma[col - 1024] * val;
                    else
                        out_o[row * 2048 + (col - 2048)] = f2bf(val);
                }
            }
        }
    }
}

// ---------------- chunked complex scan (3 passes total over h-planes) -------
// h_t = f*h_{t-1} + in_t per (b,channel). NCHUNK chunks of CHLEN steps.
// pass A (read-only): local scan per chunk, emit final state as carry.
__global__ __launch_bounds__(256) void scan_carries(
    const float* __restrict__ in_r, const float* __restrict__ in_i,
    float* __restrict__ carry,
    const float* __restrict__ fr_, const float* __restrict__ fi_) {
    int t = blockIdx.x * 256 + threadIdx.x;  // BB*1024*NCHUNK
    int c = t & 1023;
    int ck = (t >> 10) & (NCHUNK - 1);
    int b = t >> 15;                          // 1024*NCHUNK = 32768 = 2^15
    float fr = fr_[c], fi = fi_[c];
    size_t base = ((size_t)(b * TT + ck * CHLEN)) * 1024 + c;
    float hr = 0.f, hi = 0.f;
#pragma unroll 4
    for (int j = 0; j < CHLEN; ++j) {
        size_t idx = base + (size_t)j * 1024;
        float r = in_r[idx], im = in_i[idx];
        float nhr = fr * hr - fi * hi + r;
        float nhi = fr * hi + fi * hr + im;
        hr = nhr; hi = nhi;
    }
    size_t ci = (((size_t)b * 1024 + c) * NCHUNK + ck) * 2;
    carry[ci] = hr; carry[ci + 1] = hi;
}

// pass B: recompute carry-in from chunk summaries, rescan chunk with that
// start state, write h in place.
__global__ __launch_bounds__(256) void scan_apply(
    float* __restrict__ h_r, float* __restrict__ h_i,
    const float* __restrict__ carry,
    const float* __restrict__ fr_, const float* __restrict__ fi_) {
    int t = blockIdx.x * 256 + threadIdx.x;
    int c = t & 1023;
    int ck = (t >> 10) & (NCHUNK - 1);
    int b = t >> 15;
    float fr = fr_[c], fi = fi_[c];
    // A = f^CHLEN by repeated squaring (CHLEN = 64 = 2^6)
    float ar = fr, ai = fi;
#pragma unroll
    for (int s = 0; s < 6; ++s) {
        float nr = ar * ar - ai * ai, ni = 2.f * ar * ai;
        ar = nr; ai = ni;
    }
    float Hr = 0.f, Hi = 0.f;
    size_t cb = ((size_t)b * 1024 + c) * NCHUNK * 2;
    for (int k = 0; k < ck; ++k) {
        float cr = carry[cb + k * 2], cim = carry[cb + k * 2 + 1];
        float nHr = ar * Hr - ai * Hi + cr;
        float nHi = ar * Hi + ai * Hr + cim;
        Hr = nHr; Hi = nHi;
    }
    size_t base = ((size_t)(b * TT + ck * CHLEN)) * 1024 + c;
    float hr = Hr, hi = Hi;
#pragma unroll 4
    for (int j = 0; j < CHLEN; ++j) {
        size_t idx = base + (size_t)j * 1024;
        float r = h_r[idx], im = h_i[idx];
        float nhr = fr * hr - fi * hi + r;
        float nhi = fr * hi + fi * hr + im;
        hr = nhr; hi = nhi;
        h_r[idx] = hr; h_i[idx] = hi;
    }
}

// ---------------- silu-gate + LayerNorm -> bf16 y ----------------
__global__ __launch_bounds__(256) void ln_fuse(
    const float* __restrict__ hr, const float* __restrict__ hi,
    const ushort* __restrict__ o, const float* __restrict__ lnw,
    const float* __restrict__ lnb, ushort* __restrict__ yb) {
    long row = blockIdx.x;
    int tid = threadIdx.x;
    float y[8];
    float s = 0.f, s2 = 0.f;
#pragma unroll
    for (int j = 0; j < 8; ++j) {
        int c = tid + j * 256;                  // 0..2047
        float ov = bf2f(o[row * 2048 + c]);
        float sg = 1.f / (1.f + __expf(-ov));
        float h = (j < 4) ? hr[row * 1024 + c] : hi[row * 1024 + c - 1024];
        float v = h * ov * sg;
        y[j] = v; s += v; s2 += v * v;
    }
#pragma unroll
    for (int off = 32; off > 0; off >>= 1) {
        s += __shfl_down(s, off, 64);
        s2 += __shfl_down(s2, off, 64);
    }
    __shared__ float red[8];
    int wv = tid >> 6;
    if ((tid & 63) == 0) { red[wv] = s; red[4 + wv] = s2; }
    __syncthreads();
    if (tid == 0) {
        red[0] = red[0] + red[1] + red[2] + red[3];
        red[4] = red[4] + red[5] + red[6] + red[7];
    }
    __syncthreads();
    s = red[0]; s2 = red[4];
    float mu = s * (1.f / 2048.f);
    float var = s2 * (1.f / 2048.f) - mu * mu;
    float rs = rsqrtf(var + 1e-5f);
#pragma unroll
    for (int j = 0; j < 8; ++j) {
        int c = tid + j * 256;
        float v = (y[j] - mu) * rs * lnw[c] + lnb[c];
        yb[row * 2048 + c] = f2bf(v);
    }
}

// ---------------- launch ----------------

extern "C" void kernel_launch(void* const* d_in, const int* in_sizes, int n_in,
                              void* d_out, int out_size, void* d_ws, size_t ws_size,
                              hipStream_t stream) {
    const float* x         = (const float*)d_in[0];
    const float* W_in      = (const float*)d_in[1];
    const float* b_in      = (const float*)d_in[2];
    const float* nu_log    = (const float*)d_in[3];
    const float* theta_log = (const float*)d_in[4];
    const float* gamma_log = (const float*)d_in[5];
    const float* ln_w      = (const float*)d_in[6];
    const float* ln_b      = (const float*)d_in[7];
    const float* W_out     = (const float*)d_in[8];
    const float* b_out     = (const float*)d_in[9];
    float* out = (float*)d_out;

    char* ws = (char*)d_ws;
    size_t off = 0;
    auto alloc = [&](size_t bytes) {
        char* p = ws + off;
        off += (bytes + 255) & ~(size_t)255;
        return p;
    };
    ushort* xb    = (ushort*)alloc((size_t)ROWS * 1024 * 2);
    ushort* WinT  = (ushort*)alloc((size_t)4096 * 1024 * 2);
    ushort* WoutT = (ushort*)alloc((size_t)1024 * 2048 * 2);
    float*  fr    = (float*)alloc(1024 * 4);
    float*  fi    = (float*)alloc(1024 * 4);
    float*  gm    = (float*)alloc(1024 * 4);
    float*  in_r  = (float*)alloc((size_t)ROWS * 1024 * 4);    // h_r after scan
    float*  in_i  = (float*)alloc((size_t)ROWS * 1024 * 4);
    ushort* obuf  = (ushort*)alloc((size_t)ROWS * 2048 * 2);
    float*  carry = (float*)alloc((size_t)BB * 1024 * NCHUNK * 2 * 4);
    ushort* yb    = (ushort*)alloc((size_t)ROWS * 2048 * 2);

    cvt_x<<<ROWS * 1024 / 4 / 256, 256, 0, stream>>>(x, xb);
    transp_cvt<<<dim3(4096 / 32, 1024 / 32), 256, 0, stream>>>(W_in, WinT, 1024, 4096);
    transp_cvt<<<dim3(1024 / 32, 2048 / 32), 256, 0, stream>>>(W_out, WoutT, 2048, 1024);
    consts_k<<<4, 256, 0, stream>>>(nu_log, theta_log, gamma_log, fr, fi, gm);

    gemm_bf16<<<dim3(4096 / 128, ROWS / 128), 256, 0, stream>>>(
        xb, WinT, 1024, 4096, b_in, 1, gm, in_r, in_i, obuf, nullptr);

    scan_carries<<<BB * 1024 * NCHUNK / 256, 256, 0, stream>>>(in_r, in_i, carry, fr, fi);
    scan_apply<<<BB * 1024 * NCHUNK / 256, 256, 0, stream>>>(in_r, in_i, carry, fr, fi);

    ln_fuse<<<ROWS, 256, 0, stream>>>(in_r, in_i, obuf, ln_w, ln_b, yb);

    gemm_bf16<<<dim3(1024 / 128, ROWS / 128), 256, 0, stream>>>(
        yb, WoutT, 2048, 1024, b_out, 0, nullptr, nullptr, nullptr, nullptr, out);
}

// Round 4
// 346.700 us; speedup vs baseline: 1.0607x; 1.0313x over previous
//
#include <hip/hip_runtime.h>
#include <hip/hip_bf16.h>

#define D_MODEL 1024
#define BB 4
#define TT 2048
#define ROWS (BB*TT)     /* 8192 */
#define NCHUNK 32
#define CHLEN 64         /* NCHUNK*CHLEN == TT */

typedef __attribute__((ext_vector_type(8))) short short8;
typedef __attribute__((ext_vector_type(4))) float floatx4;

static __device__ __forceinline__ ushort f2bf(float f) {
    union { float f; unsigned u; } v; v.f = f;
    unsigned r = v.u + 0x7FFF + ((v.u >> 16) & 1);   // RNE
    return (ushort)(r >> 16);
}
static __device__ __forceinline__ float bf2f(ushort b) {
    union { unsigned u; float f; } v; v.u = ((unsigned)b) << 16;
    return v.f;
}

// async global->LDS, 16B per lane; LDS dest is wave-uniform base + lane*16
#define GLOAD_LDS16(gp, lp)                                                 \
    __builtin_amdgcn_global_load_lds(                                       \
        (const __attribute__((address_space(1))) void*)(gp),                \
        (__attribute__((address_space(3))) void*)(lp), 16, 0, 0)

// ---------------- prep kernels ----------------

__global__ __launch_bounds__(256) void cvt_x(const float* __restrict__ x,
                                             ushort* __restrict__ xb) {
    int i = blockIdx.x * 256 + threadIdx.x;      // 1 float4 each
    float4 v = ((const float4*)x)[i];
    ushort4 o;
    o.x = f2bf(v.x); o.y = f2bf(v.y); o.z = f2bf(v.z); o.w = f2bf(v.w);
    ((ushort4*)xb)[i] = o;
}

// W: K x N (row-major) fp32  ->  WT: N x K (row-major) bf16
__global__ __launch_bounds__(256) void transp_cvt(const float* __restrict__ W,
                                                  ushort* __restrict__ WT,
                                                  int K, int N) {
    __shared__ float tile[32][33];
    int n0 = blockIdx.x * 32, k0 = blockIdx.y * 32;
    int tx = threadIdx.x & 31, ty = threadIdx.x >> 5;   // ty 0..7
#pragma unroll
    for (int j = 0; j < 4; ++j)
        tile[ty + j*8][tx] = W[(size_t)(k0 + ty + j*8) * N + n0 + tx];
    __syncthreads();
#pragma unroll
    for (int j = 0; j < 4; ++j)
        WT[(size_t)(n0 + ty + j*8) * K + k0 + tx] = f2bf(tile[tx][ty + j*8]);
}

__global__ void consts_k(const float* __restrict__ nu_log,
                         const float* __restrict__ theta_log,
                         const float* __restrict__ gamma_log,
                         float* __restrict__ fr, float* __restrict__ fi,
                         float* __restrict__ gm) {
    int c = blockIdx.x * 256 + threadIdx.x;
    if (c < D_MODEL) {
        float nu = expf(-expf(nu_log[c]));
        float th = expf(theta_log[c]);
        fr[c] = nu * cosf(th);
        fi[c] = nu * sinf(th);
        gm[c] = expf(gamma_log[c]);
    }
}

// ------- bf16 MFMA GEMM (128x128 tile, BK=32, async staging, XOR swizzle) ---
// LDS(row,p) holds global k-chunk (row, p ^ sw(row)), sw(row)=(row>>1)&3,
// 16B chunks within a 64B row. Kills the 8-way ds_read_b128 bank conflict
// (row stride 64B = 16 banks) while keeping global 64B-coalescing and the
// global_load_lds lane*16 LDS-dest constraint.
// mode 0: outC[row*N+col] = acc + bias[col]
// mode 1: GEMM1 split epilogue (N=4096): cols [0,1024)->bf16(gamma*val)->out_r;
//         [1024,2048)->bf16(gamma*val)->out_i; [2048,4096)->bf16 out_o.
__global__ __launch_bounds__(256) void gemm_bf16(
    const ushort* __restrict__ A, const ushort* __restrict__ B,
    int K, int N, const float* __restrict__ bias, int mode,
    const float* __restrict__ gamma,
    ushort* __restrict__ out_r, ushort* __restrict__ out_i,
    ushort* __restrict__ out_o, float* __restrict__ outC) {
    __shared__ ushort As[128 * 32];
    __shared__ ushort Bs[128 * 32];
    int tid = threadIdx.x;
    int lane = tid & 63, wave = tid >> 6;
    int wm = (wave & 1) * 64, wn = (wave >> 1) * 64;
    int lr = lane & 15, q = lane >> 4;
    long m0 = (long)blockIdx.y * 128;
    long n0 = (long)blockIdx.x * 128;
    floatx4 acc[4][4] = {};

    int r0 = tid >> 2;
    int c0 = (((tid & 3) ^ ((r0 >> 1) & 3)) * 8);   // swizzled global k-chunk
    const ushort* Ap = A + (m0 + r0) * (long)K + c0;
    const ushort* Bp = B + (n0 + r0) * (long)K + c0;

    int swl = (lr >> 1) & 3;                         // read-side swizzle
    int qs8 = (q ^ swl) * 8;

    for (int kt = 0; kt < K; kt += 32) {
        __syncthreads();
        GLOAD_LDS16(Ap + kt,                 &As[tid * 8]);
        GLOAD_LDS16(Ap + (long)64 * K + kt,  &As[tid * 8 + 2048]);
        GLOAD_LDS16(Bp + kt,                 &Bs[tid * 8]);
        GLOAD_LDS16(Bp + (long)64 * K + kt,  &Bs[tid * 8 + 2048]);
        __syncthreads();
        short8 af[4], bfv[4];
#pragma unroll
        for (int r = 0; r < 4; ++r)
            af[r] = *(const short8*)&As[(wm + r * 16 + lr) * 32 + qs8];
#pragma unroll
        for (int c = 0; c < 4; ++c)
            bfv[c] = *(const short8*)&Bs[(wn + c * 16 + lr) * 32 + qs8];
#pragma unroll
        for (int r = 0; r < 4; ++r)
#pragma unroll
            for (int c = 0; c < 4; ++c)
                acc[r][c] = __builtin_amdgcn_mfma_f32_16x16x32_bf16(
                    af[r], bfv[c], acc[r][c], 0, 0, 0);
    }

#pragma unroll
    for (int r = 0; r < 4; ++r) {
#pragma unroll
        for (int c = 0; c < 4; ++c) {
            long col = n0 + wn + c * 16 + lr;
            float bv = bias[col];
#pragma unroll
            for (int g = 0; g < 4; ++g) {
                long row = m0 + wm + r * 16 + q * 4 + g;
                float val = acc[r][c][g] + bv;
                if (mode == 0) {
                    outC[row * (long)N + col] = val;
                } else {
                    if (col < 1024)
                        out_r[row * 1024 + col] = f2bf(gamma[col] * val);
                    else if (col < 2048)
                        out_i[row * 1024 + (col - 1024)] = f2bf(gamma[col - 1024] * val);
                    else
                        out_o[row * 2048 + (col - 2048)] = f2bf(val);
                }
            }
        }
    }
}

// ---------------- chunked complex scan (bf16 planes, fp32 accum) ------------
// h_t = f*h_{t-1} + in_t per (b,channel). NCHUNK chunks of CHLEN steps.
// pass A (read-only): local scan per chunk, emit final state as fp32 carry.
__global__ __launch_bounds__(256) void scan_carries(
    const ushort* __restrict__ in_r, const ushort* __restrict__ in_i,
    float* __restrict__ carry,
    const float* __restrict__ fr_, const float* __restrict__ fi_) {
    int t = blockIdx.x * 256 + threadIdx.x;  // BB*1024*NCHUNK
    int c = t & 1023;
    int ck = (t >> 10) & (NCHUNK - 1);
    int b = t >> 15;                          // 1024*NCHUNK = 32768 = 2^15
    float fr = fr_[c], fi = fi_[c];
    size_t base = ((size_t)(b * TT + ck * CHLEN)) * 1024 + c;
    float hr = 0.f, hi = 0.f;
#pragma unroll 4
    for (int j = 0; j < CHLEN; ++j) {
        size_t idx = base + (size_t)j * 1024;
        float r = bf2f(in_r[idx]), im = bf2f(in_i[idx]);
        float nhr = fr * hr - fi * hi + r;
        float nhi = fr * hi + fi * hr + im;
        hr = nhr; hi = nhi;
    }
    size_t ci = (((size_t)b * 1024 + c) * NCHUNK + ck) * 2;
    carry[ci] = hr; carry[ci + 1] = hi;
}

// pass B: recompute carry-in from chunk summaries, rescan chunk with that
// start state, write bf16 h in place.
__global__ __launch_bounds__(256) void scan_apply(
    ushort* __restrict__ h_r, ushort* __restrict__ h_i,
    const float* __restrict__ carry,
    const float* __restrict__ fr_, const float* __restrict__ fi_) {
    int t = blockIdx.x * 256 + threadIdx.x;
    int c = t & 1023;
    int ck = (t >> 10) & (NCHUNK - 1);
    int b = t >> 15;
    float fr = fr_[c], fi = fi_[c];
    // A = f^CHLEN by repeated squaring (CHLEN = 64 = 2^6)
    float ar = fr, ai = fi;
#pragma unroll
    for (int s = 0; s < 6; ++s) {
        float nr = ar * ar - ai * ai, ni = 2.f * ar * ai;
        ar = nr; ai = ni;
    }
    float Hr = 0.f, Hi = 0.f;
    size_t cb = ((size_t)b * 1024 + c) * NCHUNK * 2;
    for (int k = 0; k < ck; ++k) {
        float cr = carry[cb + k * 2], cim = carry[cb + k * 2 + 1];
        float nHr = ar * Hr - ai * Hi + cr;
        float nHi = ar * Hi + ai * Hr + cim;
        Hr = nHr; Hi = nHi;
    }
    size_t base = ((size_t)(b * TT + ck * CHLEN)) * 1024 + c;
    float hr = Hr, hi = Hi;
#pragma unroll 4
    for (int j = 0; j < CHLEN; ++j) {
        size_t idx = base + (size_t)j * 1024;
        float r = bf2f(h_r[idx]), im = bf2f(h_i[idx]);
        float nhr = fr * hr - fi * hi + r;
        float nhi = fr * hi + fi * hr + im;
        hr = nhr; hi = nhi;
        h_r[idx] = f2bf(hr); h_i[idx] = f2bf(hi);
    }
}

// ---------------- silu-gate + LayerNorm -> bf16 y ----------------
__global__ __launch_bounds__(256) void ln_fuse(
    const ushort* __restrict__ hr, const ushort* __restrict__ hi,
    const ushort* __restrict__ o, const float* __restrict__ lnw,
    const float* __restrict__ lnb, ushort* __restrict__ yb) {
    long row = blockIdx.x;
    int tid = threadIdx.x;
    float y[8];
    float s = 0.f, s2 = 0.f;
#pragma unroll
    for (int j = 0; j < 8; ++j) {
        int c = tid + j * 256;                  // 0..2047
        float ov = bf2f(o[row * 2048 + c]);
        float sg = 1.f / (1.f + __expf(-ov));
        float h = (j < 4) ? bf2f(hr[row * 1024 + c]) : bf2f(hi[row * 1024 + c - 1024]);
        float v = h * ov * sg;
        y[j] = v; s += v; s2 += v * v;
    }
#pragma unroll
    for (int off = 32; off > 0; off >>= 1) {
        s += __shfl_down(s, off, 64);
        s2 += __shfl_down(s2, off, 64);
    }
    __shared__ float red[8];
    int wv = tid >> 6;
    if ((tid & 63) == 0) { red[wv] = s; red[4 + wv] = s2; }
    __syncthreads();
    if (tid == 0) {
        red[0] = red[0] + red[1] + red[2] + red[3];
        red[4] = red[4] + red[5] + red[6] + red[7];
    }
    __syncthreads();
    s = red[0]; s2 = red[4];
    float mu = s * (1.f / 2048.f);
    float var = s2 * (1.f / 2048.f) - mu * mu;
    float rs = rsqrtf(var + 1e-5f);
#pragma unroll
    for (int j = 0; j < 8; ++j) {
        int c = tid + j * 256;
        float v = (y[j] - mu) * rs * lnw[c] + lnb[c];
        yb[row * 2048 + c] = f2bf(v);
    }
}

// ---------------- launch ----------------

extern "C" void kernel_launch(void* const* d_in, const int* in_sizes, int n_in,
                              void* d_out, int out_size, void* d_ws, size_t ws_size,
                              hipStream_t stream) {
    const float* x         = (const float*)d_in[0];
    const float* W_in      = (const float*)d_in[1];
    const float* b_in      = (const float*)d_in[2];
    const float* nu_log    = (const float*)d_in[3];
    const float* theta_log = (const float*)d_in[4];
    const float* gamma_log = (const float*)d_in[5];
    const float* ln_w      = (const float*)d_in[6];
    const float* ln_b      = (const float*)d_in[7];
    const float* W_out     = (const float*)d_in[8];
    const float* b_out     = (const float*)d_in[9];
    float* out = (float*)d_out;

    char* ws = (char*)d_ws;
    size_t off = 0;
    auto alloc = [&](size_t bytes) {
        char* p = ws + off;
        off += (bytes + 255) & ~(size_t)255;
        return p;
    };
    ushort* xb    = (ushort*)alloc((size_t)ROWS * 1024 * 2);
    ushort* WinT  = (ushort*)alloc((size_t)4096 * 1024 * 2);
    ushort* WoutT = (ushort*)alloc((size_t)1024 * 2048 * 2);
    float*  fr    = (float*)alloc(1024 * 4);
    float*  fi    = (float*)alloc(1024 * 4);
    float*  gm    = (float*)alloc(1024 * 4);
    ushort* in_r  = (ushort*)alloc((size_t)ROWS * 1024 * 2);   // bf16; h after scan
    ushort* in_i  = (ushort*)alloc((size_t)ROWS * 1024 * 2);
    ushort* obuf  = (ushort*)alloc((size_t)ROWS * 2048 * 2);
    float*  carry = (float*)alloc((size_t)BB * 1024 * NCHUNK * 2 * 4);
    ushort* yb    = (ushort*)alloc((size_t)ROWS * 2048 * 2);

    cvt_x<<<ROWS * 1024 / 4 / 256, 256, 0, stream>>>(x, xb);
    transp_cvt<<<dim3(4096 / 32, 1024 / 32), 256, 0, stream>>>(W_in, WinT, 1024, 4096);
    transp_cvt<<<dim3(1024 / 32, 2048 / 32), 256, 0, stream>>>(W_out, WoutT, 2048, 1024);
    consts_k<<<4, 256, 0, stream>>>(nu_log, theta_log, gamma_log, fr, fi, gm);

    gemm_bf16<<<dim3(4096 / 128, ROWS / 128), 256, 0, stream>>>(
        xb, WinT, 1024, 4096, b_in, 1, gm, in_r, in_i, obuf, nullptr);

    scan_carries<<<BB * 1024 * NCHUNK / 256, 256, 0, stream>>>(in_r, in_i, carry, fr, fi);
    scan_apply<<<BB * 1024 * NCHUNK / 256, 256, 0, stream>>>(in_r, in_i, carry, fr, fi);

    ln_fuse<<<ROWS, 256, 0, stream>>>(in_r, in_i, obuf, ln_w, ln_b, yb);

    gemm_bf16<<<dim3(1024 / 128, ROWS / 128), 256, 0, stream>>>(
        yb, WoutT, 2048, 1024, b_out, 0, nullptr, nullptr, nullptr, nullptr, out);
}

// Round 5
// 307.539 us; speedup vs baseline: 1.1958x; 1.1273x over previous
//
#include <hip/hip_runtime.h>
#include <hip/hip_bf16.h>

#define D_MODEL 1024
#define BB 4
#define TT 2048
#define ROWS (BB*TT)     /* 8192 */
#define NCHUNK 32
#define CHLEN 64         /* NCHUNK*CHLEN == TT */

typedef __attribute__((ext_vector_type(8))) short short8;
typedef __attribute__((ext_vector_type(4))) float floatx4;

static __device__ __forceinline__ ushort f2bf(float f) {
    union { float f; unsigned u; } v; v.f = f;
    unsigned r = v.u + 0x7FFF + ((v.u >> 16) & 1);   // RNE
    return (ushort)(r >> 16);
}
static __device__ __forceinline__ float bf2f(ushort b) {
    union { unsigned u; float f; } v; v.u = ((unsigned)b) << 16;
    return v.f;
}

// async global->LDS, 16B per lane; LDS dest is wave-uniform base + lane*16
#define GLOAD_LDS16(gp, lp)                                                 \
    __builtin_amdgcn_global_load_lds(                                       \
        (const __attribute__((address_space(1))) void*)(gp),                \
        (__attribute__((address_space(3))) void*)(lp), 16, 0, 0)

// ---------------- prep kernels ----------------

__global__ __launch_bounds__(256) void cvt_x(const float* __restrict__ x,
                                             ushort* __restrict__ xb) {
    int i = blockIdx.x * 256 + threadIdx.x;      // 1 float4 each
    float4 v = ((const float4*)x)[i];
    ushort4 o;
    o.x = f2bf(v.x); o.y = f2bf(v.y); o.z = f2bf(v.z); o.w = f2bf(v.w);
    ((ushort4*)xb)[i] = o;
}

// W: K x N (row-major) fp32  ->  WT: N x K (row-major) bf16
__global__ __launch_bounds__(256) void transp_cvt(const float* __restrict__ W,
                                                  ushort* __restrict__ WT,
                                                  int K, int N) {
    __shared__ float tile[32][33];
    int n0 = blockIdx.x * 32, k0 = blockIdx.y * 32;
    int tx = threadIdx.x & 31, ty = threadIdx.x >> 5;   // ty 0..7
#pragma unroll
    for (int j = 0; j < 4; ++j)
        tile[ty + j*8][tx] = W[(size_t)(k0 + ty + j*8) * N + n0 + tx];
    __syncthreads();
#pragma unroll
    for (int j = 0; j < 4; ++j)
        WT[(size_t)(n0 + ty + j*8) * K + k0 + tx] = f2bf(tile[tx][ty + j*8]);
}

__global__ void consts_k(const float* __restrict__ nu_log,
                         const float* __restrict__ theta_log,
                         const float* __restrict__ gamma_log,
                         float* __restrict__ fr, float* __restrict__ fi,
                         float* __restrict__ gm) {
    int c = blockIdx.x * 256 + threadIdx.x;
    if (c < D_MODEL) {
        float nu = expf(-expf(nu_log[c]));
        float th = expf(theta_log[c]);
        fr[c] = nu * cosf(th);
        fi[c] = nu * sinf(th);
        gm[c] = expf(gamma_log[c]);
    }
}

// ------- bf16 MFMA GEMM (128x128 tile, BK=64, async staging, XOR swizzle) ---
// LDS row = 64 bf16 = 128 B = 8 16B-chunks. LDS(row,p) holds global chunk
// (row, p ^ (row&7)): staging stays 128B-coalesced + lane*16-contiguous,
// ds_read_b128 lands 2-way per bank group (free).
// mode 0: outC[row*N+col] = acc + bias[col]
// mode 1: GEMM1 split epilogue (N=4096), sector=(n0+wn)>>10 wave-uniform:
//   sector 0 -> bf16(gamma*val) -> out_r; 1 -> out_i; 2,3 -> bf16 val -> out_o.
__global__ __launch_bounds__(256) void gemm_bf16(
    const ushort* __restrict__ A, const ushort* __restrict__ B,
    int K, int N, const float* __restrict__ bias, int mode,
    const float* __restrict__ gamma,
    ushort* __restrict__ out_r, ushort* __restrict__ out_i,
    ushort* __restrict__ out_o, float* __restrict__ outC) {
    __shared__ ushort As[128 * 64];
    __shared__ ushort Bs[128 * 64];
    int tid = threadIdx.x;
    int lane = tid & 63, wave = tid >> 6;
    int wm = (wave & 1) * 64, wn = (wave >> 1) * 64;
    int lr = lane & 15, q = lane >> 4;
    long m0 = (long)blockIdx.y * 128;
    long n0 = (long)blockIdx.x * 128;
    floatx4 acc[4][4] = {};

    // staging geometry: chunk_id = j*256 + tid  ->  row = j*32 + (tid>>3),
    // stored global chunk = (tid&7) ^ (row&7); row&7 == (tid>>3)&7.
    int rs = tid >> 3;
    int pg = ((tid & 7) ^ (rs & 7)) * 8;
    const ushort* Ap = A + (m0 + rs) * (long)K + pg;
    const ushort* Bp = B + (n0 + rs) * (long)K + pg;
    int swl = lr & 7;    // read-side swizzle: LDS chunk = global chunk ^ swl

    for (int kt = 0; kt < K; kt += 64) {
        __syncthreads();
#pragma unroll
        for (int j = 0; j < 4; ++j) {
            GLOAD_LDS16(Ap + kt + (long)(j * 32) * K, &As[(j * 256 + tid) * 8]);
            GLOAD_LDS16(Bp + kt + (long)(j * 32) * K, &Bs[(j * 256 + tid) * 8]);
        }
        __syncthreads();
#pragma unroll
        for (int s = 0; s < 2; ++s) {
            short8 af[4], bfv[4];
            int pq = ((s * 4 + q) ^ swl) * 8;
#pragma unroll
            for (int r = 0; r < 4; ++r)
                af[r] = *(const short8*)&As[(wm + r * 16 + lr) * 64 + pq];
#pragma unroll
            for (int c = 0; c < 4; ++c)
                bfv[c] = *(const short8*)&Bs[(wn + c * 16 + lr) * 64 + pq];
#pragma unroll
            for (int r = 0; r < 4; ++r)
#pragma unroll
                for (int c = 0; c < 4; ++c)
                    acc[r][c] = __builtin_amdgcn_mfma_f32_16x16x32_bf16(
                        af[r], bfv[c], acc[r][c], 0, 0, 0);
        }
    }

    if (mode == 0) {
#pragma unroll
        for (int r = 0; r < 4; ++r) {
#pragma unroll
            for (int c = 0; c < 4; ++c) {
                long col = n0 + wn + c * 16 + lr;
                float bv = bias[col];
#pragma unroll
                for (int g = 0; g < 4; ++g) {
                    long row = m0 + wm + r * 16 + q * 4 + g;
                    outC[row * (long)N + col] = acc[r][c][g] + bv;
                }
            }
        }
    } else {
        int sector = (int)((n0 + wn) >> 10);          // wave-uniform
        int lc0 = (int)((n0 + wn) & 1023);
        if (sector < 2) {
            ushort* dst = sector ? out_i : out_r;
#pragma unroll
            for (int r = 0; r < 4; ++r) {
#pragma unroll
                for (int c = 0; c < 4; ++c) {
                    int lc = lc0 + c * 16 + lr;
                    float bv = bias[(sector << 10) + lc];
                    float gv = gamma[lc];
#pragma unroll
                    for (int g = 0; g < 4; ++g) {
                        long row = m0 + wm + r * 16 + q * 4 + g;
                        dst[row * 1024 + lc] = f2bf(gv * (acc[r][c][g] + bv));
                    }
                }
            }
        } else {
            int oc0 = (int)(n0 + wn - 2048);
#pragma unroll
            for (int r = 0; r < 4; ++r) {
#pragma unroll
                for (int c = 0; c < 4; ++c) {
                    int oc = oc0 + c * 16 + lr;
                    float bv = bias[2048 + oc];
#pragma unroll
                    for (int g = 0; g < 4; ++g) {
                        long row = m0 + wm + r * 16 + q * 4 + g;
                        out_o[row * 2048 + oc] = f2bf(acc[r][c][g] + bv);
                    }
                }
            }
        }
    }
}

// ---------------- chunked complex scan (bf16 planes, fp32 accum) ------------
// pass A (read-only): local scan per chunk, emit final state as fp32 carry.
__global__ __launch_bounds__(256) void scan_carries(
    const ushort* __restrict__ in_r, const ushort* __restrict__ in_i,
    float* __restrict__ carry,
    const float* __restrict__ fr_, const float* __restrict__ fi_) {
    int t = blockIdx.x * 256 + threadIdx.x;  // BB*1024*NCHUNK
    int c = t & 1023;
    int ck = (t >> 10) & (NCHUNK - 1);
    int b = t >> 15;
    float fr = fr_[c], fi = fi_[c];
    size_t base = ((size_t)(b * TT + ck * CHLEN)) * 1024 + c;
    float hr = 0.f, hi = 0.f;
#pragma unroll 4
    for (int j = 0; j < CHLEN; ++j) {
        size_t idx = base + (size_t)j * 1024;
        float r = bf2f(in_r[idx]), im = bf2f(in_i[idx]);
        float nhr = fr * hr - fi * hi + r;
        float nhi = fr * hi + fi * hr + im;
        hr = nhr; hi = nhi;
    }
    size_t ci = (((size_t)b * 1024 + c) * NCHUNK + ck) * 2;
    carry[ci] = hr; carry[ci + 1] = hi;
}

// pass B: recompute carry-in from chunk summaries, rescan chunk, write bf16.
__global__ __launch_bounds__(256) void scan_apply(
    ushort* __restrict__ h_r, ushort* __restrict__ h_i,
    const float* __restrict__ carry,
    const float* __restrict__ fr_, const float* __restrict__ fi_) {
    int t = blockIdx.x * 256 + threadIdx.x;
    int c = t & 1023;
    int ck = (t >> 10) & (NCHUNK - 1);
    int b = t >> 15;
    float fr = fr_[c], fi = fi_[c];
    float ar = fr, ai = fi;     // f^CHLEN, CHLEN=64=2^6
#pragma unroll
    for (int s = 0; s < 6; ++s) {
        float nr = ar * ar - ai * ai, ni = 2.f * ar * ai;
        ar = nr; ai = ni;
    }
    float Hr = 0.f, Hi = 0.f;
    size_t cb = ((size_t)b * 1024 + c) * NCHUNK * 2;
    for (int k = 0; k < ck; ++k) {
        float cr = carry[cb + k * 2], cim = carry[cb + k * 2 + 1];
        float nHr = ar * Hr - ai * Hi + cr;
        float nHi = ar * Hi + ai * Hr + cim;
        Hr = nHr; Hi = nHi;
    }
    size_t base = ((size_t)(b * TT + ck * CHLEN)) * 1024 + c;
    float hr = Hr, hi = Hi;
#pragma unroll 4
    for (int j = 0; j < CHLEN; ++j) {
        size_t idx = base + (size_t)j * 1024;
        float r = bf2f(h_r[idx]), im = bf2f(h_i[idx]);
        float nhr = fr * hr - fi * hi + r;
        float nhi = fr * hi + fi * hr + im;
        hr = nhr; hi = nhi;
        h_r[idx] = f2bf(hr); h_i[idx] = f2bf(hi);
    }
}

// ---------------- silu-gate + LayerNorm -> bf16 y ----------------
__global__ __launch_bounds__(256) void ln_fuse(
    const ushort* __restrict__ hr, const ushort* __restrict__ hi,
    const ushort* __restrict__ o, const float* __restrict__ lnw,
    const float* __restrict__ lnb, ushort* __restrict__ yb) {
    long row = blockIdx.x;
    int tid = threadIdx.x;
    float y[8];
    float s = 0.f, s2 = 0.f;
#pragma unroll
    for (int j = 0; j < 8; ++j) {
        int c = tid + j * 256;                  // 0..2047
        float ov = bf2f(o[row * 2048 + c]);
        float sg = 1.f / (1.f + __expf(-ov));
        float h = (j < 4) ? bf2f(hr[row * 1024 + c]) : bf2f(hi[row * 1024 + c - 1024]);
        float v = h * ov * sg;
        y[j] = v; s += v; s2 += v * v;
    }
#pragma unroll
    for (int off = 32; off > 0; off >>= 1) {
        s += __shfl_down(s, off, 64);
        s2 += __shfl_down(s2, off, 64);
    }
    __shared__ float red[8];
    int wv = tid >> 6;
    if ((tid & 63) == 0) { red[wv] = s; red[4 + wv] = s2; }
    __syncthreads();
    if (tid == 0) {
        red[0] = red[0] + red[1] + red[2] + red[3];
        red[4] = red[4] + red[5] + red[6] + red[7];
    }
    __syncthreads();
    s = red[0]; s2 = red[4];
    float mu = s * (1.f / 2048.f);
    float var = s2 * (1.f / 2048.f) - mu * mu;
    float rs = rsqrtf(var + 1e-5f);
#pragma unroll
    for (int j = 0; j < 8; ++j) {
        int c = tid + j * 256;
        float v = (y[j] - mu) * rs * lnw[c] + lnb[c];
        yb[row * 2048 + c] = f2bf(v);
    }
}

// ---------------- launch ----------------

extern "C" void kernel_launch(void* const* d_in, const int* in_sizes, int n_in,
                              void* d_out, int out_size, void* d_ws, size_t ws_size,
                              hipStream_t stream) {
    const float* x         = (const float*)d_in[0];
    const float* W_in      = (const float*)d_in[1];
    const float* b_in      = (const float*)d_in[2];
    const float* nu_log    = (const float*)d_in[3];
    const float* theta_log = (const float*)d_in[4];
    const float* gamma_log = (const float*)d_in[5];
    const float* ln_w      = (const float*)d_in[6];
    const float* ln_b      = (const float*)d_in[7];
    const float* W_out     = (const float*)d_in[8];
    const float* b_out     = (const float*)d_in[9];
    float* out = (float*)d_out;

    char* ws = (char*)d_ws;
    size_t off = 0;
    auto alloc = [&](size_t bytes) {
        char* p = ws + off;
        off += (bytes + 255) & ~(size_t)255;
        return p;
    };
    ushort* xb    = (ushort*)alloc((size_t)ROWS * 1024 * 2);
    ushort* WinT  = (ushort*)alloc((size_t)4096 * 1024 * 2);
    ushort* WoutT = (ushort*)alloc((size_t)1024 * 2048 * 2);
    float*  fr    = (float*)alloc(1024 * 4);
    float*  fi    = (float*)alloc(1024 * 4);
    float*  gm    = (float*)alloc(1024 * 4);
    ushort* in_r  = (ushort*)alloc((size_t)ROWS * 1024 * 2);   // bf16; h after scan
    ushort* in_i  = (ushort*)alloc((size_t)ROWS * 1024 * 2);
    ushort* obuf  = (ushort*)alloc((size_t)ROWS * 2048 * 2);
    float*  carry = (float*)alloc((size_t)BB * 1024 * NCHUNK * 2 * 4);
    ushort* yb    = (ushort*)alloc((size_t)ROWS * 2048 * 2);

    cvt_x<<<ROWS * 1024 / 4 / 256, 256, 0, stream>>>(x, xb);
    transp_cvt<<<dim3(4096 / 32, 1024 / 32), 256, 0, stream>>>(W_in, WinT, 1024, 4096);
    transp_cvt<<<dim3(1024 / 32, 2048 / 32), 256, 0, stream>>>(W_out, WoutT, 2048, 1024);
    consts_k<<<4, 256, 0, stream>>>(nu_log, theta_log, gamma_log, fr, fi, gm);

    gemm_bf16<<<dim3(4096 / 128, ROWS / 128), 256, 0, stream>>>(
        xb, WinT, 1024, 4096, b_in, 1, gm, in_r, in_i, obuf, nullptr);

    scan_carries<<<BB * 1024 * NCHUNK / 256, 256, 0, stream>>>(in_r, in_i, carry, fr, fi);
    scan_apply<<<BB * 1024 * NCHUNK / 256, 256, 0, stream>>>(in_r, in_i, carry, fr, fi);

    ln_fuse<<<ROWS, 256, 0, stream>>>(in_r, in_i, obuf, ln_w, ln_b, yb);

    gemm_bf16<<<dim3(1024 / 128, ROWS / 128), 256, 0, stream>>>(
        yb, WoutT, 2048, 1024, b_out, 0, nullptr, nullptr, nullptr, nullptr, out);
}

// Round 6
// 296.778 us; speedup vs baseline: 1.2392x; 1.0363x over previous
//
#include <hip/hip_runtime.h>
#include <hip/hip_bf16.h>

#define D_MODEL 1024
#define BB 4
#define TT 2048
#define ROWS (BB*TT)     /* 8192 */
#define NCHUNK 32
#define CHLEN 64         /* NCHUNK*CHLEN == TT */

typedef __attribute__((ext_vector_type(8))) short short8;
typedef __attribute__((ext_vector_type(4))) float floatx4;

static __device__ __forceinline__ ushort f2bf(float f) {
    union { float f; unsigned u; } v; v.f = f;
    unsigned r = v.u + 0x7FFF + ((v.u >> 16) & 1);   // RNE
    return (ushort)(r >> 16);
}
static __device__ __forceinline__ float bf2f(ushort b) {
    union { unsigned u; float f; } v; v.u = ((unsigned)b) << 16;
    return v.f;
}

// async global->LDS, 16B per lane; LDS dest is wave-uniform base + lane*16
#define GLOAD_LDS16(gp, lp)                                                 \
    __builtin_amdgcn_global_load_lds(                                       \
        (const __attribute__((address_space(1))) void*)(gp),                \
        (__attribute__((address_space(3))) void*)(lp), 16, 0, 0)

// ---------------- fused prep ----------------
// sections (by blockIdx.x):
//  [0, 8192)            : x fp32 -> bf16 (float4/thread)
//  [8192, 8192+4096)    : W_in (1024x4096) -> WinT (4096x1024) bf16
//  [12288, 12288+2048)  : W_out (2048x1024) -> W1T[n][k]=bf16(lnw[k]*W) and
//                         atomic s1[n]=sum lnw*W, c2[n]=sum lnb*W
//  [14336, 14336+4)     : per-channel consts fr/fi/gm
#define PREP_A 8192
#define PREP_B 4096
#define PREP_C 2048
__global__ __launch_bounds__(256) void prep_all(
    const float* __restrict__ x, ushort* __restrict__ xb,
    const float* __restrict__ W_in, ushort* __restrict__ WinT,
    const float* __restrict__ W_out, ushort* __restrict__ W1T,
    const float* __restrict__ lnw, const float* __restrict__ lnb,
    float* __restrict__ s1, float* __restrict__ c2,
    const float* __restrict__ nu_log, const float* __restrict__ theta_log,
    const float* __restrict__ gamma_log,
    float* __restrict__ fr, float* __restrict__ fi, float* __restrict__ gm) {
    __shared__ float smem[32 * 33 + 8 * 32 * 2];
    int bid = blockIdx.x, tid = threadIdx.x;
    if (bid < PREP_A) {
        int i = bid * 256 + tid;
        float4 v = ((const float4*)x)[i];
        ushort4 o;
        o.x = f2bf(v.x); o.y = f2bf(v.y); o.z = f2bf(v.z); o.w = f2bf(v.w);
        ((ushort4*)xb)[i] = o;
    } else if (bid < PREP_A + PREP_B) {
        int b2 = bid - PREP_A;                  // W_in: K=1024, N=4096
        int n0 = (b2 & 127) * 32, k0 = (b2 >> 7) * 32;
        int tx = tid & 31, ty = tid >> 5;
        float (*tile)[33] = (float (*)[33])smem;
#pragma unroll
        for (int j = 0; j < 4; ++j)
            tile[ty + j*8][tx] = W_in[(size_t)(k0 + ty + j*8) * 4096 + n0 + tx];
        __syncthreads();
#pragma unroll
        for (int j = 0; j < 4; ++j)
            WinT[(size_t)(n0 + ty + j*8) * 1024 + k0 + tx] = f2bf(tile[tx][ty + j*8]);
    } else if (bid < PREP_A + PREP_B + PREP_C) {
        int b2 = bid - PREP_A - PREP_B;         // W_out: K=2048, N=1024
        int n0 = (b2 & 31) * 32, k0 = (b2 >> 5) * 32;
        int tx = tid & 31, ty = tid >> 5;
        float (*tile)[33] = (float (*)[33])smem;
        float* red1 = smem + 32 * 33;
        float* red2 = red1 + 8 * 32;
        float p1 = 0.f, p2 = 0.f;              // col sums for n = n0+tx
#pragma unroll
        for (int j = 0; j < 4; ++j) {
            int k = k0 + ty + j * 8;
            float w = W_out[(size_t)k * 1024 + n0 + tx];
            float lw = lnw[k], lb = lnb[k];
            tile[ty + j*8][tx] = lw * w;
            p1 += lw * w; p2 += lb * w;
        }
        __syncthreads();
#pragma unroll
        for (int j = 0; j < 4; ++j)
            W1T[(size_t)(n0 + ty + j*8) * 2048 + k0 + tx] = f2bf(tile[tx][ty + j*8]);
        red1[ty * 32 + tx] = p1; red2[ty * 32 + tx] = p2;
        __syncthreads();
        if (ty == 0) {
            float a = 0.f, b = 0.f;
#pragma unroll
            for (int t = 0; t < 8; ++t) { a += red1[t * 32 + tx]; b += red2[t * 32 + tx]; }
            atomicAdd(&s1[n0 + tx], a);
            atomicAdd(&c2[n0 + tx], b);
        }
    } else {
        int c = (bid - PREP_A - PREP_B - PREP_C) * 256 + tid;
        if (c < D_MODEL) {
            float nu = expf(-expf(nu_log[c]));
            float th = expf(theta_log[c]);
            fr[c] = nu * cosf(th);
            fi[c] = nu * sinf(th);
            gm[c] = expf(gamma_log[c]);
        }
    }
}

// ------- bf16 MFMA GEMM (128x128 tile, BK=64, async staging, XOR swizzle) ---
// LDS row = 64 bf16 = 128 B = 8 16B-chunks; LDS(row,p) = global chunk
// (row, p ^ (row&7)) -> conflict-free ds_read_b128, coalesced staging.
// mode 1: GEMM1 split epilogue (N=4096), sector=(n0+wn)>>10 wave-uniform:
//   sector 0 -> bf16(gamma*val)->out_r; 1 -> out_i; 2,3 -> bf16 val -> out_o.
// mode 2: GEMM2 LN-folded epilogue:
//   out[row][col] = rs[row]*(acc - mu[row]*s1[col]) + c2[col] + bias[col]
__global__ __launch_bounds__(256) void gemm_bf16(
    const ushort* __restrict__ A, const ushort* __restrict__ B,
    int K, int N, const float* __restrict__ bias, int mode,
    const float* __restrict__ gamma,
    ushort* __restrict__ out_r, ushort* __restrict__ out_i,
    ushort* __restrict__ out_o, float* __restrict__ outC,
    const float* __restrict__ mu, const float* __restrict__ rs,
    const float* __restrict__ s1, const float* __restrict__ c2) {
    __shared__ ushort As[128 * 64];
    __shared__ ushort Bs[128 * 64];
    int tid = threadIdx.x;
    int lane = tid & 63, wave = tid >> 6;
    int wm = (wave & 1) * 64, wn = (wave >> 1) * 64;
    int lr = lane & 15, q = lane >> 4;
    long m0 = (long)blockIdx.y * 128;
    long n0 = (long)blockIdx.x * 128;
    floatx4 acc[4][4] = {};

    int rs_ = tid >> 3;
    int pg = ((tid & 7) ^ (rs_ & 7)) * 8;
    const ushort* Ap = A + (m0 + rs_) * (long)K + pg;
    const ushort* Bp = B + (n0 + rs_) * (long)K + pg;
    int swl = lr & 7;

    for (int kt = 0; kt < K; kt += 64) {
        __syncthreads();
#pragma unroll
        for (int j = 0; j < 4; ++j) {
            GLOAD_LDS16(Ap + kt + (long)(j * 32) * K, &As[(j * 256 + tid) * 8]);
            GLOAD_LDS16(Bp + kt + (long)(j * 32) * K, &Bs[(j * 256 + tid) * 8]);
        }
        __syncthreads();
#pragma unroll
        for (int s = 0; s < 2; ++s) {
            short8 af[4], bfv[4];
            int pq = ((s * 4 + q) ^ swl) * 8;
#pragma unroll
            for (int r = 0; r < 4; ++r)
                af[r] = *(const short8*)&As[(wm + r * 16 + lr) * 64 + pq];
#pragma unroll
            for (int c = 0; c < 4; ++c)
                bfv[c] = *(const short8*)&Bs[(wn + c * 16 + lr) * 64 + pq];
#pragma unroll
            for (int r = 0; r < 4; ++r)
#pragma unroll
                for (int c = 0; c < 4; ++c)
                    acc[r][c] = __builtin_amdgcn_mfma_f32_16x16x32_bf16(
                        af[r], bfv[c], acc[r][c], 0, 0, 0);
        }
    }

    if (mode == 2) {
#pragma unroll
        for (int r = 0; r < 4; ++r) {
#pragma unroll
            for (int c = 0; c < 4; ++c) {
                long col = n0 + wn + c * 16 + lr;
                float bc = c2[col] + bias[col];
                float s1c = s1[col];
#pragma unroll
                for (int g = 0; g < 4; ++g) {
                    long row = m0 + wm + r * 16 + q * 4 + g;
                    outC[row * (long)N + col] =
                        rs[row] * (acc[r][c][g] - mu[row] * s1c) + bc;
                }
            }
        }
    } else {
        int sector = (int)((n0 + wn) >> 10);          // wave-uniform
        int lc0 = (int)((n0 + wn) & 1023);
        if (sector < 2) {
            ushort* dst = sector ? out_i : out_r;
#pragma unroll
            for (int r = 0; r < 4; ++r) {
#pragma unroll
                for (int c = 0; c < 4; ++c) {
                    int lc = lc0 + c * 16 + lr;
                    float bv = bias[(sector << 10) + lc];
                    float gv = gamma[lc];
#pragma unroll
                    for (int g = 0; g < 4; ++g) {
                        long row = m0 + wm + r * 16 + q * 4 + g;
                        dst[row * 1024 + lc] = f2bf(gv * (acc[r][c][g] + bv));
                    }
                }
            }
        } else {
            int oc0 = (int)(n0 + wn - 2048);
#pragma unroll
            for (int r = 0; r < 4; ++r) {
#pragma unroll
                for (int c = 0; c < 4; ++c) {
                    int oc = oc0 + c * 16 + lr;
                    float bv = bias[2048 + oc];
#pragma unroll
                    for (int g = 0; g < 4; ++g) {
                        long row = m0 + wm + r * 16 + q * 4 + g;
                        out_o[row * 2048 + oc] = f2bf(acc[r][c][g] + bv);
                    }
                }
            }
        }
    }
}

// ---------------- chunked complex scan (bf16 planes, fp32 accum) ------------
// pass A (read-only): local scan per chunk, emit final state as fp32 carry.
__global__ __launch_bounds__(256) void scan_carries(
    const ushort* __restrict__ in_r, const ushort* __restrict__ in_i,
    float* __restrict__ carry,
    const float* __restrict__ fr_, const float* __restrict__ fi_) {
    int t = blockIdx.x * 256 + threadIdx.x;  // BB*1024*NCHUNK
    int c = t & 1023;
    int ck = (t >> 10) & (NCHUNK - 1);
    int b = t >> 15;
    float fr = fr_[c], fi = fi_[c];
    size_t base = ((size_t)(b * TT + ck * CHLEN)) * 1024 + c;
    float hr = 0.f, hi = 0.f;
#pragma unroll 4
    for (int j = 0; j < CHLEN; ++j) {
        size_t idx = base + (size_t)j * 1024;
        float r = bf2f(in_r[idx]), im = bf2f(in_i[idx]);
        float nhr = fr * hr - fi * hi + r;
        float nhi = fr * hi + fi * hr + im;
        hr = nhr; hi = nhi;
    }
    size_t ci = (((size_t)b * 1024 + c) * NCHUNK + ck) * 2;
    carry[ci] = hr; carry[ci + 1] = hi;
}

// pass B: recompute carry-in, rescan chunk, emit y' = h*silu(o) (bf16, 2048-ch)
__global__ __launch_bounds__(256) void scan_apply(
    const ushort* __restrict__ in_r, const ushort* __restrict__ in_i,
    const float* __restrict__ carry,
    const float* __restrict__ fr_, const float* __restrict__ fi_,
    const ushort* __restrict__ o, ushort* __restrict__ yb) {
    int t = blockIdx.x * 256 + threadIdx.x;
    int c = t & 1023;
    int ck = (t >> 10) & (NCHUNK - 1);
    int b = t >> 15;
    float fr = fr_[c], fi = fi_[c];
    float ar = fr, ai = fi;     // f^CHLEN, CHLEN=64=2^6
#pragma unroll
    for (int s = 0; s < 6; ++s) {
        float nr = ar * ar - ai * ai, ni = 2.f * ar * ai;
        ar = nr; ai = ni;
    }
    float Hr = 0.f, Hi = 0.f;
    size_t cb = ((size_t)b * 1024 + c) * NCHUNK * 2;
    for (int k = 0; k < ck; ++k) {
        float cr = carry[cb + k * 2], cim = carry[cb + k * 2 + 1];
        float nHr = ar * Hr - ai * Hi + cr;
        float nHi = ar * Hi + ai * Hr + cim;
        Hr = nHr; Hi = nHi;
    }
    size_t base = ((size_t)(b * TT + ck * CHLEN)) * 1024 + c;
    size_t rowbase = (size_t)(b * TT + ck * CHLEN);
    float hr = Hr, hi = Hi;
#pragma unroll 2
    for (int j = 0; j < CHLEN; ++j) {
        size_t idx = base + (size_t)j * 1024;
        float r = bf2f(in_r[idx]), im = bf2f(in_i[idx]);
        float nhr = fr * hr - fi * hi + r;
        float nhi = fr * hi + fi * hr + im;
        hr = nhr; hi = nhi;
        size_t ob = (rowbase + j) * 2048 + c;
        float ov1 = bf2f(o[ob]);
        float ov2 = bf2f(o[ob + 1024]);
        float y1 = hr * ov1 / (1.f + __expf(-ov1));
        float y2 = hi * ov2 / (1.f + __expf(-ov2));
        yb[ob] = f2bf(y1);
        yb[ob + 1024] = f2bf(y2);
    }
}

// ---------------- per-row stats of y' (for folded LN) ----------------
__global__ __launch_bounds__(256) void row_stats(
    const ushort* __restrict__ yb, float* __restrict__ mu_o,
    float* __restrict__ rs_o) {
    long row = blockIdx.x;
    int tid = threadIdx.x;
    const ushort* p = yb + row * 2048 + tid * 8;
    uint4 raw = *(const uint4*)p;                 // 8 bf16
    float s = 0.f, s2 = 0.f;
    unsigned w[4] = {raw.x, raw.y, raw.z, raw.w};
#pragma unroll
    for (int j = 0; j < 4; ++j) {
        float a = bf2f((ushort)(w[j] & 0xffff));
        float b = bf2f((ushort)(w[j] >> 16));
        s += a + b; s2 += a * a + b * b;
    }
#pragma unroll
    for (int off = 32; off > 0; off >>= 1) {
        s += __shfl_down(s, off, 64);
        s2 += __shfl_down(s2, off, 64);
    }
    __shared__ float red[8];
    int wv = tid >> 6;
    if ((tid & 63) == 0) { red[wv] = s; red[4 + wv] = s2; }
    __syncthreads();
    if (tid == 0) {
        s = red[0] + red[1] + red[2] + red[3];
        s2 = red[4] + red[5] + red[6] + red[7];
        float mu = s * (1.f / 2048.f);
        float var = s2 * (1.f / 2048.f) - mu * mu;
        mu_o[row] = mu;
        rs_o[row] = rsqrtf(var + 1e-5f);
    }
}

// ---------------- launch ----------------

extern "C" void kernel_launch(void* const* d_in, const int* in_sizes, int n_in,
                              void* d_out, int out_size, void* d_ws, size_t ws_size,
                              hipStream_t stream) {
    const float* x         = (const float*)d_in[0];
    const float* W_in      = (const float*)d_in[1];
    const float* b_in      = (const float*)d_in[2];
    const float* nu_log    = (const float*)d_in[3];
    const float* theta_log = (const float*)d_in[4];
    const float* gamma_log = (const float*)d_in[5];
    const float* ln_w      = (const float*)d_in[6];
    const float* ln_b      = (const float*)d_in[7];
    const float* W_out     = (const float*)d_in[8];
    const float* b_out     = (const float*)d_in[9];
    float* out = (float*)d_out;

    char* ws = (char*)d_ws;
    size_t off = 0;
    auto alloc = [&](size_t bytes) {
        char* p = ws + off;
        off += (bytes + 255) & ~(size_t)255;
        return p;
    };
    ushort* xb    = (ushort*)alloc((size_t)ROWS * 1024 * 2);
    ushort* WinT  = (ushort*)alloc((size_t)4096 * 1024 * 2);
    ushort* W1T   = (ushort*)alloc((size_t)1024 * 2048 * 2);
    float*  fr    = (float*)alloc(1024 * 4);
    float*  fi    = (float*)alloc(1024 * 4);
    float*  gm    = (float*)alloc(1024 * 4);
    float*  s1c2  = (float*)alloc(2048 * 4);           // s1 | c2
    float*  s1    = s1c2;
    float*  c2    = s1c2 + 1024;
    ushort* in_r  = (ushort*)alloc((size_t)ROWS * 1024 * 2);
    ushort* in_i  = (ushort*)alloc((size_t)ROWS * 1024 * 2);
    ushort* obuf  = (ushort*)alloc((size_t)ROWS * 2048 * 2);
    float*  carry = (float*)alloc((size_t)BB * 1024 * NCHUNK * 2 * 4);
    ushort* yb    = (ushort*)alloc((size_t)ROWS * 2048 * 2);
    float*  muv   = (float*)alloc(ROWS * 4);
    float*  rsv   = (float*)alloc(ROWS * 4);

    hipMemsetAsync(s1c2, 0, 2048 * 4, stream);

    prep_all<<<PREP_A + PREP_B + PREP_C + 4, 256, 0, stream>>>(
        x, xb, W_in, WinT, W_out, W1T, ln_w, ln_b, s1, c2,
        nu_log, theta_log, gamma_log, fr, fi, gm);

    gemm_bf16<<<dim3(4096 / 128, ROWS / 128), 256, 0, stream>>>(
        xb, WinT, 1024, 4096, b_in, 1, gm, in_r, in_i, obuf, nullptr,
        nullptr, nullptr, nullptr, nullptr);

    scan_carries<<<BB * 1024 * NCHUNK / 256, 256, 0, stream>>>(in_r, in_i, carry, fr, fi);
    scan_apply<<<BB * 1024 * NCHUNK / 256, 256, 0, stream>>>(
        in_r, in_i, carry, fr, fi, obuf, yb);

    row_stats<<<ROWS, 256, 0, stream>>>(yb, muv, rsv);

    gemm_bf16<<<dim3(1024 / 128, ROWS / 128), 256, 0, stream>>>(
        yb, W1T, 2048, 1024, b_out, 2, nullptr, nullptr, nullptr, nullptr, out,
        muv, rsv, s1, c2);
}